// Round 2
// baseline (1622.829 us; speedup 1.0000x reference)
//
#include <hip/hip_runtime.h>

#define N_NODES 500000
#define N_EDGES 8000000
#define EPSF 1e-8f

struct Accum { double pde_sum, bc_sum, bc_cnt, j1_sum, j2_sum, het_cnt; };

__device__ __forceinline__ int xcc_id() {
    int v;
    asm("s_getreg_b32 %0, hwreg(HW_REG_XCC_ID)" : "=s"(v));
    return v & 7;
}

// Block-wide f64 sum. Valid result on thread 0 only.
__device__ double block_reduce(double v) {
    __shared__ double sm[16];
    __syncthreads();
    for (int off = 32; off; off >>= 1) v += __shfl_down(v, off, 64);
    const int lane = threadIdx.x & 63, wid = threadIdx.x >> 6;
    if (lane == 0) sm[wid] = v;
    __syncthreads();
    if (wid == 0) {
        const int nw = blockDim.x >> 6;
        v = (lane < nw) ? sm[lane] : 0.0;
        for (int off = 8; off; off >>= 1) v += __shfl_down(v, off, 64);
    }
    return v;
}

// Compact per-node sign(z) and beta (replaces strided gathers into x[:,3]).
__global__ void prep(const float* __restrict__ x,
                     const float* __restrict__ bm_p, const float* __restrict__ bp_p,
                     float* __restrict__ signz, float* __restrict__ beta) {
    const float bm = bm_p[0], bp = bp_p[0];
    const int stride = gridDim.x * blockDim.x;
    for (int i = blockIdx.x * blockDim.x + threadIdx.x; i < N_NODES; i += stride) {
        const float z = x[4 * i + 3];
        signz[i] = (float)(z > 0.f) - (float)(z < 0.f);
        beta[i]  = (z < 0.f) ? bm : bp;
    }
}

// Pass 1: scatter dx/dy/lap into per-XCD replica (L2-local atomics), j1 loss.
template<int LOCAL>
__global__ void edge_pass1(const float* __restrict__ u,
                           const float* __restrict__ signz,
                           const float* __restrict__ j1,
                           const float4* __restrict__ cdx4,
                           const float4* __restrict__ cdy4,
                           const float4* __restrict__ clap4,
                           const int4* __restrict__ row4,
                           const int4* __restrict__ col4,
                           const int4* __restrict__ attr4,
                           float* __restrict__ rep,
                           Accum* __restrict__ acc) {
    float* mine = LOCAL ? rep + (size_t)xcc_id() * ((size_t)N_NODES * 4) : rep;
    double j1s = 0.0;
    long hc = 0;
    const int stride = gridDim.x * blockDim.x;
    const int NV = N_EDGES / 4;
    for (int q = blockIdx.x * blockDim.x + threadIdx.x; q < NV; q += stride) {
        const int4 r4 = row4[q], c4 = col4[q], a4 = attr4[q];
        const float4 cx4 = cdx4[q], cy4 = cdy4[q], cl4 = clap4[q];
        const int*   rr = (const int*)&r4;
        const int*   cc = (const int*)&c4;
        const int*   aa = (const int*)&a4;
        const float* fx = (const float*)&cx4;
        const float* fy = (const float*)&cy4;
        const float* fl = (const float*)&cl4;
#pragma unroll
        for (int k = 0; k < 4; ++k) {
            const int r = rr[k], c = cc[k];
            const float ud = u[c] - u[r];
            float* slot = mine + (size_t)r * 4;
            if (LOCAL) {
                __hip_atomic_fetch_add(slot + 0, ud * fx[k], __ATOMIC_RELAXED, __HIP_MEMORY_SCOPE_WORKGROUP);
                __hip_atomic_fetch_add(slot + 1, ud * fy[k], __ATOMIC_RELAXED, __HIP_MEMORY_SCOPE_WORKGROUP);
                __hip_atomic_fetch_add(slot + 2, ud * fl[k], __ATOMIC_RELAXED, __HIP_MEMORY_SCOPE_WORKGROUP);
            } else {
                atomicAdd(slot + 0, ud * fx[k]);
                atomicAdd(slot + 1, ud * fy[k]);
                atomicAdd(slot + 2, ud * fl[k]);
            }
            if (aa[k] == 1) {
                const float d = signz[c] * ud - j1[r];
                j1s += (double)(d * d);
                hc  += 1;
            }
        }
    }
    double t = block_reduce(j1s);
    if (threadIdx.x == 0) atomicAdd(&acc->j1_sum, t);
    t = block_reduce((double)hc);
    if (threadIdx.x == 0) atomicAdd(&acc->het_cnt, t);
}

// Sum replicas -> fin, fused with node losses (pde, bc).
__global__ void reduce_node(const float4* __restrict__ rep, int nrep,
                            const float* __restrict__ u,
                            const float2* __restrict__ pos,
                            const float* __restrict__ y,
                            const float* __restrict__ source,
                            const float* __restrict__ beta,
                            float4* __restrict__ fin,
                            Accum* __restrict__ acc) {
    double pde = 0.0, bcs = 0.0;
    long bcc = 0;
    const int stride = gridDim.x * blockDim.x;
    for (int i = blockIdx.x * blockDim.x + threadIdx.x; i < N_NODES; i += stride) {
        float dx = 0.f, dy = 0.f, lp = 0.f;
        for (int k = 0; k < nrep; ++k) {
            const float4 v = rep[(size_t)k * N_NODES + i];
            dx += v.x; dy += v.y; lp += v.z;
        }
        fin[i] = make_float4(dx, dy, lp, 0.f);
        const float res = -lp - source[i] / beta[i];
        pde += (double)(res * res);
        const float2 p = pos[i];
        if (fabsf(p.x) > 0.99f || fabsf(p.y) > 0.99f) {
            const float d = u[i] - y[i];
            bcs += (double)(d * d);
            bcc += 1;
        }
    }
    double t = block_reduce(pde);
    if (threadIdx.x == 0) atomicAdd(&acc->pde_sum, t);
    t = block_reduce(bcs);
    if (threadIdx.x == 0) atomicAdd(&acc->bc_sum, t);
    t = block_reduce((double)bcc);
    if (threadIdx.x == 0) atomicAdd(&acc->bc_cnt, t);
}

// Pass 2: flux-jump loss over het edges (needs completed dx/dy in fin).
__global__ void edge_pass2(const float2* __restrict__ pos,
                           const int4* __restrict__ row4,
                           const int4* __restrict__ col4,
                           const int4* __restrict__ attr4,
                           const float* __restrict__ signz,
                           const float* __restrict__ beta,
                           const float4* __restrict__ fin,
                           const float* __restrict__ a_p, const float* __restrict__ b_p,
                           const float* __restrict__ c_p,
                           const float* __restrict__ bm_p, const float* __restrict__ bp_p,
                           Accum* __restrict__ acc) {
    const float a = a_p[0], b = b_p[0], cw = c_p[0], bm = bm_p[0], bp = bp_p[0];
    const float inva2 = 1.f / (a * a), invb2 = 1.f / (b * b);
    const float tgt = 2.f * (cw * bp - bm);
    double j2s = 0.0;
    const int stride = gridDim.x * blockDim.x;
    const int NV = N_EDGES / 4;
    for (int q = blockIdx.x * blockDim.x + threadIdx.x; q < NV; q += stride) {
        const int4 r4 = row4[q], c4 = col4[q], a4 = attr4[q];
        const int* rr = (const int*)&r4;
        const int* cc = (const int*)&c4;
        const int* aa = (const int*)&a4;
#pragma unroll
        for (int k = 0; k < 4; ++k) {
            if (aa[k] != 1) continue;
            const int r = rr[k], c = cc[k];
            const float2 pr = pos[r], pc = pos[c];
            const float nx = 0.5f * (pr.x + pc.x) * inva2;
            const float ny = 0.5f * (pr.y + pc.y) * invb2;
            const float nrm = fmaxf(sqrtf(nx * nx + ny * ny), EPSF);
            const float inv = 1.f / nrm;
            const float nxu = nx * inv, nyu = ny * inv;
            const float4 fr = fin[r], fc = fin[c];
            const float dn_s = fr.x * nxu + fr.y * nyu;
            const float dn_d = fc.x * nxu + fc.y * nyu;
            const float flux = signz[c] * (beta[c] * dn_d - beta[r] * dn_s);
            const float d = flux - tgt * nrm;
            j2s += (double)(d * d);
        }
    }
    const double t = block_reduce(j2s);
    if (threadIdx.x == 0) atomicAdd(&acc->j2_sum, t);
}

__global__ void finalize(const Accum* __restrict__ acc, float* __restrict__ out) {
    if (threadIdx.x == 0 && blockIdx.x == 0) {
        const double loss_pde = acc->pde_sum / (double)N_NODES;
        const double loss_bc  = acc->bc_sum / fmax(acc->bc_cnt, 1.0);
        const double hc       = fmax(acc->het_cnt, 1.0);
        const double loss_j1  = acc->j1_sum / hc;
        const double loss_j2  = acc->j2_sum / hc;
        out[0] = (float)(1.0 * loss_pde + 100.0 * loss_bc + 10.0 * loss_j1 + 10.0 * loss_j2);
    }
}

extern "C" void kernel_launch(void* const* d_in, const int* in_sizes, int n_in,
                              void* d_out, int out_size, void* d_ws, size_t ws_size,
                              hipStream_t stream) {
    const float* u_pred = (const float*)d_in[0];
    const float* x      = (const float*)d_in[1];
    const float* pos    = (const float*)d_in[2];
    const float* y      = (const float*)d_in[3];
    const float* source = (const float*)d_in[4];
    const float* j1     = (const float*)d_in[5];
    const float* cdx    = (const float*)d_in[6];
    const float* cdy    = (const float*)d_in[7];
    const float* clap   = (const float*)d_in[8];
    const float* a_p    = (const float*)d_in[9];
    const float* b_p    = (const float*)d_in[10];
    const float* c_p    = (const float*)d_in[11];
    const float* bm_p   = (const float*)d_in[12];
    const float* bp_p   = (const float*)d_in[13];
    const int* edge_index = (const int*)d_in[14];
    const int* eattr      = (const int*)d_in[15];
    const int* row_idx = edge_index;
    const int* col_idx = edge_index + N_EDGES;

    // Workspace layout: rep[nrep * N_NODES float4] | Accum(pad to 64) | fin | signz | beta
    const size_t repOne = (size_t)N_NODES * 16;
    const size_t tailSz = 64 + repOne + 2 * (size_t)N_NODES * 4;
    const int nrep = (ws_size >= 8 * repOne + tailSz) ? 8 : 1;
    const size_t repBytes = (size_t)nrep * repOne;

    char* base = (char*)d_ws;
    float*  rep   = (float*)base;
    Accum*  acc   = (Accum*)(base + repBytes);
    float4* fin   = (float4*)(base + repBytes + 64);
    float*  signz = (float*)(base + repBytes + 64 + repOne);
    float*  beta  = signz + N_NODES;

    // zero replicas + accumulators (ws is NOT re-poisoned between replays)
    hipMemsetAsync(d_ws, 0, repBytes + 64, stream);

    const int threads = 256;
    const int nblocks = (N_NODES + threads - 1) / threads;
    const int eblocks = 2048;

    prep<<<nblocks, threads, 0, stream>>>(x, bm_p, bp_p, signz, beta);

    if (nrep == 8) {
        edge_pass1<1><<<eblocks, threads, 0, stream>>>(
            u_pred, signz, j1,
            (const float4*)cdx, (const float4*)cdy, (const float4*)clap,
            (const int4*)row_idx, (const int4*)col_idx, (const int4*)eattr,
            rep, acc);
    } else {
        edge_pass1<0><<<eblocks, threads, 0, stream>>>(
            u_pred, signz, j1,
            (const float4*)cdx, (const float4*)cdy, (const float4*)clap,
            (const int4*)row_idx, (const int4*)col_idx, (const int4*)eattr,
            rep, acc);
    }

    reduce_node<<<nblocks, threads, 0, stream>>>((const float4*)rep, nrep,
                                                 u_pred, (const float2*)pos, y,
                                                 source, beta, fin, acc);

    edge_pass2<<<eblocks, threads, 0, stream>>>((const float2*)pos,
                                                (const int4*)row_idx, (const int4*)col_idx,
                                                (const int4*)eattr,
                                                signz, beta, fin,
                                                a_p, b_p, c_p, bm_p, bp_p, acc);

    finalize<<<1, 64, 0, stream>>>(acc, (float*)d_out);
}

// Round 3
// 841.640 us; speedup vs baseline: 1.9282x; 1.9282x over previous
//
#include <hip/hip_runtime.h>

#define N_NODES 500000
#define N_EDGES 8000000
#define EPSF 1e-8f

#define WIN_SHIFT 11
#define WINDOW 2048                    // nodes per bucket
#define NB 245                         // ceil(500000/2048)
#define CHUNK 8000                     // edges per scatter chunk
#define NCHUNK 1000                    // 8e6 / 8000 exactly

struct Accum { double pde_sum, bc_sum, bc_cnt, j1_sum, j2_sum, het_cnt; };

__device__ __forceinline__ int xcc_id() {
    int v;
    asm("s_getreg_b32 %0, hwreg(HW_REG_XCC_ID)" : "=s"(v));
    return v & 7;
}

// Block-wide f64 sum. Valid on thread 0 only.
__device__ double block_reduce(double v) {
    __shared__ double sm[16];
    __syncthreads();
    for (int off = 32; off; off >>= 1) v += __shfl_down(v, off, 64);
    const int lane = threadIdx.x & 63, wid = threadIdx.x >> 6;
    if (lane == 0) sm[wid] = v;
    __syncthreads();
    if (wid == 0) {
        const int nw = blockDim.x >> 6;
        v = (lane < nw) ? sm[lane] : 0.0;
        for (int off = 8; off; off >>= 1) v += __shfl_down(v, off, 64);
    }
    return v;
}

// per-node (signz, beta) packed
__global__ void prep(const float* __restrict__ x,
                     const float* __restrict__ bm_p, const float* __restrict__ bp_p,
                     float2* __restrict__ bs) {
    const float bm = bm_p[0], bp = bp_p[0];
    const int stride = gridDim.x * blockDim.x;
    for (int i = blockIdx.x * blockDim.x + threadIdx.x; i < N_NODES; i += stride) {
        const float z = x[4 * i + 3];
        bs[i] = make_float2((float)(z > 0.f) - (float)(z < 0.f), (z < 0.f) ? bm : bp);
    }
}

// ---------------- sort path ----------------

__global__ void k_hist(const int* __restrict__ row, const int* __restrict__ attr,
                       unsigned int* __restrict__ hist, unsigned int* __restrict__ hist_het) {
    __shared__ unsigned int h[NB];
    __shared__ unsigned int hh;
    for (int i = threadIdx.x; i < NB; i += blockDim.x) h[i] = 0;
    if (threadIdx.x == 0) hh = 0;
    __syncthreads();
    const int ch = blockIdx.x;
    const int e1 = min(ch * CHUNK + CHUNK, N_EDGES);
    unsigned int myhet = 0;
    for (int e = ch * CHUNK + threadIdx.x; e < e1; e += blockDim.x) {
        atomicAdd(&h[row[e] >> WIN_SHIFT], 1u);
        if (attr[e] == 1) myhet++;
    }
    if (myhet) atomicAdd(&hh, myhet);
    __syncthreads();
    for (int i = threadIdx.x; i < NB; i += blockDim.x) hist[(size_t)i * NCHUNK + ch] = h[i];
    if (threadIdx.x == 0) hist_het[ch] = hh;
}

// per-bucket exclusive scan across chunks
__global__ void k_scan1(const unsigned int* __restrict__ hist,
                        unsigned int* __restrict__ scanned,
                        unsigned int* __restrict__ total) {
    __shared__ unsigned int v[NCHUNK];
    const int b = blockIdx.x;
    for (int i = threadIdx.x; i < NCHUNK; i += blockDim.x) v[i] = hist[(size_t)b * NCHUNK + i];
    __syncthreads();
    if (threadIdx.x == 0) {
        unsigned int s = 0;
        for (int i = 0; i < NCHUNK; ++i) { unsigned int t = v[i]; v[i] = s; s += t; }
        total[b] = s;
    }
    __syncthreads();
    for (int i = threadIdx.x; i < NCHUNK; i += blockDim.x) scanned[(size_t)b * NCHUNK + i] = v[i];
}

// bucket bases + het bases
__global__ void k_scan2(const unsigned int* __restrict__ total,
                        const unsigned int* __restrict__ hist_het,
                        unsigned int* __restrict__ base,
                        unsigned int* __restrict__ hetbase,
                        unsigned int* __restrict__ n_het) {
    __shared__ unsigned int tl[NB];
    __shared__ unsigned int hl[NCHUNK];
    for (int i = threadIdx.x; i < NB; i += blockDim.x) tl[i] = total[i];
    for (int i = threadIdx.x; i < NCHUNK; i += blockDim.x) hl[i] = hist_het[i];
    __syncthreads();
    if (threadIdx.x == 0) {
        unsigned int s = 0;
        for (int b = 0; b < NB; ++b) { unsigned int t = tl[b]; tl[b] = s; s += t; }
        unsigned int hs = 0;
        for (int c = 0; c < NCHUNK; ++c) { unsigned int t = hl[c]; hl[c] = hs; hs += t; }
        *n_het = hs;
    }
    __syncthreads();
    for (int i = threadIdx.x; i < NB; i += blockDim.x) base[i] = tl[i];
    for (int i = threadIdx.x; i < NCHUNK; i += blockDim.x) hetbase[i] = hl[i];
}

// scatter edges into bucket-sorted records; fold j1 loss; emit compact het list
template<int COMPACT>
__global__ void k_scatter(const int* __restrict__ row, const int* __restrict__ col,
                          const int* __restrict__ attr,
                          const float* __restrict__ cdx, const float* __restrict__ cdy,
                          const float* __restrict__ clap,
                          const float* __restrict__ u, const float* __restrict__ j1,
                          const float2* __restrict__ bs,
                          const unsigned int* __restrict__ base,
                          const unsigned int* __restrict__ scanned,
                          const unsigned int* __restrict__ hetbase,
                          float4* __restrict__ rec, int2* __restrict__ het,
                          Accum* __restrict__ acc) {
    __shared__ int cur[NB];
    __shared__ int hcur;
    const int ch = blockIdx.x;
    for (int i = threadIdx.x; i < NB; i += blockDim.x)
        cur[i] = (int)(base[i] + scanned[(size_t)i * NCHUNK + ch]);
    if (COMPACT && threadIdx.x == 0) hcur = (int)hetbase[ch];
    __syncthreads();
    double j1s = 0.0;
    long hc = 0;
    const int e1 = min(ch * CHUNK + CHUNK, N_EDGES);
    for (int e = ch * CHUNK + threadIdx.x; e < e1; e += blockDim.x) {
        const int r = row[e], c = col[e];
        const float ud = u[c] - u[r];
        const int b = r >> WIN_SHIFT;
        const int p = atomicAdd(&cur[b], 1);
        rec[p] = make_float4(__uint_as_float((unsigned int)(r & (WINDOW - 1))),
                             ud * cdx[e], ud * cdy[e], ud * clap[e]);
        if (attr[e] == 1) {
            const float d = bs[c].x * ud - j1[r];
            j1s += (double)(d * d);
            hc++;
            if (COMPACT) {
                const int hp = atomicAdd(&hcur, 1);
                het[hp] = make_int2(r, c);
            }
        }
    }
    double t = block_reduce(j1s);
    if (threadIdx.x == 0) atomicAdd(&acc->j1_sum, t);
    t = block_reduce((double)hc);
    if (threadIdx.x == 0) atomicAdd(&acc->het_cnt, t);
}

// per-bucket LDS accumulate + fused node losses; write fin(dx,dy)
__global__ void k_acc(const float4* __restrict__ rec,
                      const unsigned int* __restrict__ base,
                      const unsigned int* __restrict__ total,
                      const float* __restrict__ u, const float2* __restrict__ pos2,
                      const float* __restrict__ y, const float* __restrict__ source,
                      const float2* __restrict__ bs,
                      float2* __restrict__ fin, Accum* __restrict__ acc) {
    __shared__ float a3[WINDOW * 3];
    for (int i = threadIdx.x; i < WINDOW * 3; i += blockDim.x) a3[i] = 0.f;
    __syncthreads();
    const int b = blockIdx.x;
    const int s = (int)base[b];
    const int e = s + (int)total[b];
    for (int i = s + threadIdx.x; i < e; i += blockDim.x) {
        const float4 rc = rec[i];
        const int lr = (int)__float_as_uint(rc.x) * 3;
        atomicAdd(&a3[lr + 0], rc.y);
        atomicAdd(&a3[lr + 1], rc.z);
        atomicAdd(&a3[lr + 2], rc.w);
    }
    __syncthreads();
    double pde = 0.0, bcs = 0.0;
    long bcc = 0;
    const int n0 = b << WIN_SHIFT;
    const int n1 = min(n0 + WINDOW, N_NODES);
    for (int i = n0 + threadIdx.x; i < n1; i += blockDim.x) {
        const int l = (i - n0) * 3;
        fin[i] = make_float2(a3[l], a3[l + 1]);
        const float res = -a3[l + 2] - source[i] / bs[i].y;
        pde += (double)(res * res);
        const float2 p = pos2[i];
        if (fabsf(p.x) > 0.99f || fabsf(p.y) > 0.99f) {
            const float d = u[i] - y[i];
            bcs += (double)(d * d);
            bcc++;
        }
    }
    double t = block_reduce(pde);
    if (threadIdx.x == 0) atomicAdd(&acc->pde_sum, t);
    t = block_reduce(bcs);
    if (threadIdx.x == 0) atomicAdd(&acc->bc_sum, t);
    t = block_reduce((double)bcc);
    if (threadIdx.x == 0) atomicAdd(&acc->bc_cnt, t);
}

__device__ __forceinline__ double j2_term(int r, int c,
                                          const float2* __restrict__ pos2,
                                          const float2* __restrict__ bs,
                                          const float2* __restrict__ fin,
                                          float inva2, float invb2, float tgt) {
    const float2 pr = pos2[r], pc = pos2[c];
    const float nx = 0.5f * (pr.x + pc.x) * inva2;
    const float ny = 0.5f * (pr.y + pc.y) * invb2;
    const float nrm = fmaxf(sqrtf(nx * nx + ny * ny), EPSF);
    const float inv = 1.f / nrm;
    const float nxu = nx * inv, nyu = ny * inv;
    const float2 fr = fin[r], fc = fin[c];
    const float2 br = bs[r], bc = bs[c];
    const float dn_s = fr.x * nxu + fr.y * nyu;
    const float dn_d = fc.x * nxu + fc.y * nyu;
    const float flux = bc.x * (bc.y * dn_d - br.y * dn_s);
    const float d = flux - tgt * nrm;
    return (double)(d * d);
}

// j2 over compacted het list
__global__ void k_pass2(const int2* __restrict__ het,
                        const unsigned int* __restrict__ n_het,
                        const float2* __restrict__ pos2, const float2* __restrict__ bs,
                        const float2* __restrict__ fin,
                        const float* __restrict__ a_p, const float* __restrict__ b_p,
                        const float* __restrict__ c_p,
                        const float* __restrict__ bm_p, const float* __restrict__ bp_p,
                        Accum* __restrict__ acc) {
    const float a = a_p[0], b = b_p[0], cw = c_p[0], bm = bm_p[0], bp = bp_p[0];
    const float inva2 = 1.f / (a * a), invb2 = 1.f / (b * b);
    const float tgt = 2.f * (cw * bp - bm);
    const int tot = (int)*n_het;
    double j2s = 0.0;
    const int stride = gridDim.x * blockDim.x;
    for (int i = blockIdx.x * blockDim.x + threadIdx.x; i < tot; i += stride) {
        const int2 e = het[i];
        j2s += j2_term(e.x, e.y, pos2, bs, fin, inva2, invb2, tgt);
    }
    const double t = block_reduce(j2s);
    if (threadIdx.x == 0) atomicAdd(&acc->j2_sum, t);
}

// j2 over raw edge arrays (mid tier, no compaction)
__global__ void k_pass2_raw(const int* __restrict__ row, const int* __restrict__ col,
                            const int* __restrict__ attr,
                            const float2* __restrict__ pos2, const float2* __restrict__ bs,
                            const float2* __restrict__ fin,
                            const float* __restrict__ a_p, const float* __restrict__ b_p,
                            const float* __restrict__ c_p,
                            const float* __restrict__ bm_p, const float* __restrict__ bp_p,
                            Accum* __restrict__ acc) {
    const float a = a_p[0], b = b_p[0], cw = c_p[0], bm = bm_p[0], bp = bp_p[0];
    const float inva2 = 1.f / (a * a), invb2 = 1.f / (b * b);
    const float tgt = 2.f * (cw * bp - bm);
    double j2s = 0.0;
    const int stride = gridDim.x * blockDim.x;
    for (int e = blockIdx.x * blockDim.x + threadIdx.x; e < N_EDGES; e += stride) {
        if (attr[e] != 1) continue;
        j2s += j2_term(row[e], col[e], pos2, bs, fin, inva2, invb2, tgt);
    }
    const double t = block_reduce(j2s);
    if (threadIdx.x == 0) atomicAdd(&acc->j2_sum, t);
}

// ---------------- fallback (small ws): replicated global atomics ----------------

template<int LOCAL>
__global__ void fb_edge1(const float* __restrict__ u, const float2* __restrict__ bs,
                         const float* __restrict__ j1,
                         const float* __restrict__ cdx, const float* __restrict__ cdy,
                         const float* __restrict__ clap,
                         const int* __restrict__ row, const int* __restrict__ col,
                         const int* __restrict__ attr,
                         float* __restrict__ rep, Accum* __restrict__ acc) {
    float* mine = LOCAL ? rep + (size_t)xcc_id() * ((size_t)N_NODES * 4) : rep;
    double j1s = 0.0;
    long hc = 0;
    const int stride = gridDim.x * blockDim.x;
    for (int e = blockIdx.x * blockDim.x + threadIdx.x; e < N_EDGES; e += stride) {
        const int r = row[e], c = col[e];
        const float ud = u[c] - u[r];
        float* slot = mine + (size_t)r * 4;
        if (LOCAL) {
            __hip_atomic_fetch_add(slot + 0, ud * cdx[e], __ATOMIC_RELAXED, __HIP_MEMORY_SCOPE_WORKGROUP);
            __hip_atomic_fetch_add(slot + 1, ud * cdy[e], __ATOMIC_RELAXED, __HIP_MEMORY_SCOPE_WORKGROUP);
            __hip_atomic_fetch_add(slot + 2, ud * clap[e], __ATOMIC_RELAXED, __HIP_MEMORY_SCOPE_WORKGROUP);
        } else {
            atomicAdd(slot + 0, ud * cdx[e]);
            atomicAdd(slot + 1, ud * cdy[e]);
            atomicAdd(slot + 2, ud * clap[e]);
        }
        if (attr[e] == 1) {
            const float d = bs[c].x * ud - j1[r];
            j1s += (double)(d * d);
            hc++;
        }
    }
    double t = block_reduce(j1s);
    if (threadIdx.x == 0) atomicAdd(&acc->j1_sum, t);
    t = block_reduce((double)hc);
    if (threadIdx.x == 0) atomicAdd(&acc->het_cnt, t);
}

__global__ void fb_reduce(const float4* __restrict__ rep, int nrep,
                          const float* __restrict__ u, const float2* __restrict__ pos2,
                          const float* __restrict__ y, const float* __restrict__ source,
                          const float2* __restrict__ bs,
                          float2* __restrict__ fin, Accum* __restrict__ acc) {
    double pde = 0.0, bcs = 0.0;
    long bcc = 0;
    const int stride = gridDim.x * blockDim.x;
    for (int i = blockIdx.x * blockDim.x + threadIdx.x; i < N_NODES; i += stride) {
        float dxv = 0.f, dyv = 0.f, lp = 0.f;
        for (int k = 0; k < nrep; ++k) {
            const float4 v = rep[(size_t)k * N_NODES + i];
            dxv += v.x; dyv += v.y; lp += v.z;
        }
        fin[i] = make_float2(dxv, dyv);
        const float res = -lp - source[i] / bs[i].y;
        pde += (double)(res * res);
        const float2 p = pos2[i];
        if (fabsf(p.x) > 0.99f || fabsf(p.y) > 0.99f) {
            const float d = u[i] - y[i];
            bcs += (double)(d * d);
            bcc++;
        }
    }
    double t = block_reduce(pde);
    if (threadIdx.x == 0) atomicAdd(&acc->pde_sum, t);
    t = block_reduce(bcs);
    if (threadIdx.x == 0) atomicAdd(&acc->bc_sum, t);
    t = block_reduce((double)bcc);
    if (threadIdx.x == 0) atomicAdd(&acc->bc_cnt, t);
}

__global__ void finalize(const Accum* __restrict__ acc, float* __restrict__ out) {
    if (threadIdx.x == 0 && blockIdx.x == 0) {
        const double loss_pde = acc->pde_sum / (double)N_NODES;
        const double loss_bc  = acc->bc_sum / fmax(acc->bc_cnt, 1.0);
        const double hc       = fmax(acc->het_cnt, 1.0);
        out[0] = (float)(loss_pde + 100.0 * loss_bc + 10.0 * (acc->j1_sum / hc) + 10.0 * (acc->j2_sum / hc));
    }
}

extern "C" void kernel_launch(void* const* d_in, const int* in_sizes, int n_in,
                              void* d_out, int out_size, void* d_ws, size_t ws_size,
                              hipStream_t stream) {
    const float* u_pred = (const float*)d_in[0];
    const float* x      = (const float*)d_in[1];
    const float2* pos2  = (const float2*)d_in[2];
    const float* y      = (const float*)d_in[3];
    const float* source = (const float*)d_in[4];
    const float* j1     = (const float*)d_in[5];
    const float* cdx    = (const float*)d_in[6];
    const float* cdy    = (const float*)d_in[7];
    const float* clap   = (const float*)d_in[8];
    const float* a_p    = (const float*)d_in[9];
    const float* b_p    = (const float*)d_in[10];
    const float* c_p    = (const float*)d_in[11];
    const float* bm_p   = (const float*)d_in[12];
    const float* bp_p   = (const float*)d_in[13];
    const int* row_idx  = (const int*)d_in[14];
    const int* col_idx  = row_idx + N_EDGES;
    const int* eattr    = (const int*)d_in[15];

    char* base_p = (char*)d_ws;
    size_t off = 0;
    auto alloc = [&](size_t bytes) { void* p = base_p + off; off = (off + bytes + 15) & ~(size_t)15; return p; };

    Accum* acc = (Accum*)alloc(sizeof(Accum));
    float2* fin = (float2*)alloc((size_t)N_NODES * 8);
    float2* bs  = (float2*)alloc((size_t)N_NODES * 8);
    unsigned int* hist     = (unsigned int*)alloc((size_t)NB * NCHUNK * 4);
    unsigned int* scanned  = (unsigned int*)alloc((size_t)NB * NCHUNK * 4);
    unsigned int* total    = (unsigned int*)alloc(NB * 4);
    unsigned int* baseb    = (unsigned int*)alloc(NB * 4);
    unsigned int* hist_het = (unsigned int*)alloc(NCHUNK * 4);
    unsigned int* hetbase  = (unsigned int*)alloc(NCHUNK * 4);
    unsigned int* n_het    = (unsigned int*)alloc(4);
    const size_t misc_end = off;
    float4* rec = (float4*)alloc((size_t)N_EDGES * 16);
    const size_t need_mid = off;
    int2* het = (int2*)alloc((size_t)N_EDGES * 8);
    const size_t need_full = off;

    const int threads = 256;
    const int nblocks = (N_NODES + threads - 1) / threads;

    hipMemsetAsync(d_ws, 0, sizeof(Accum), stream);
    prep<<<nblocks, threads, 0, stream>>>(x, bm_p, bp_p, bs);

    if (ws_size >= need_mid) {
        k_hist<<<NCHUNK, threads, 0, stream>>>(row_idx, eattr, hist, hist_het);
        k_scan1<<<NB, threads, 0, stream>>>(hist, scanned, total);
        k_scan2<<<1, threads, 0, stream>>>(total, hist_het, baseb, hetbase, n_het);
        if (ws_size >= need_full) {
            k_scatter<1><<<NCHUNK, threads, 0, stream>>>(row_idx, col_idx, eattr, cdx, cdy, clap,
                                                         u_pred, j1, bs, baseb, scanned, hetbase,
                                                         rec, het, acc);
        } else {
            k_scatter<0><<<NCHUNK, threads, 0, stream>>>(row_idx, col_idx, eattr, cdx, cdy, clap,
                                                         u_pred, j1, bs, baseb, scanned, hetbase,
                                                         rec, het, acc);
        }
        k_acc<<<NB, threads, 0, stream>>>(rec, baseb, total, u_pred, pos2, y, source, bs, fin, acc);
        if (ws_size >= need_full) {
            k_pass2<<<1024, threads, 0, stream>>>(het, n_het, pos2, bs, fin,
                                                  a_p, b_p, c_p, bm_p, bp_p, acc);
        } else {
            k_pass2_raw<<<2048, threads, 0, stream>>>(row_idx, col_idx, eattr, pos2, bs, fin,
                                                      a_p, b_p, c_p, bm_p, bp_p, acc);
        }
    } else {
        // fallback: replicated global atomics
        const size_t repOne = (size_t)N_NODES * 16;
        float* rep = (float*)(base_p + misc_end);
        const int nrep = (ws_size >= misc_end + 8 * repOne) ? 8 : 1;
        hipMemsetAsync(rep, 0, (size_t)nrep * repOne, stream);
        if (nrep == 8)
            fb_edge1<1><<<2048, threads, 0, stream>>>(u_pred, bs, j1, cdx, cdy, clap,
                                                      row_idx, col_idx, eattr, rep, acc);
        else
            fb_edge1<0><<<2048, threads, 0, stream>>>(u_pred, bs, j1, cdx, cdy, clap,
                                                      row_idx, col_idx, eattr, rep, acc);
        fb_reduce<<<nblocks, threads, 0, stream>>>((const float4*)rep, nrep, u_pred, pos2, y,
                                                   source, bs, fin, acc);
        k_pass2_raw<<<2048, threads, 0, stream>>>(row_idx, col_idx, eattr, pos2, bs, fin,
                                                  a_p, b_p, c_p, bm_p, bp_p, acc);
    }

    finalize<<<1, 64, 0, stream>>>(acc, (float*)d_out);
}

// Round 4
// 578.535 us; speedup vs baseline: 2.8051x; 1.4548x over previous
//
#include <hip/hip_runtime.h>

#define N_NODES 500000
#define N_EDGES 8000000
#define EPSF 1e-8f

#define WIN_SHIFT 11
#define WINDOW 2048
#define NB 245                       // ceil(500000/2048)
#define CHUNK 2000                   // edges per scatter chunk
#define NQ (CHUNK / 4)               // int4 quads per chunk
#define NCHUNK 4000                  // 8e6 / 2000
#define SC_ITEMS 16                  // 256*16 >= NCHUNK

struct Accum { double pde_sum, bc_sum, bc_cnt, j1_sum, j2_sum, het_cnt; };

// Block-wide f64 sum. Valid on thread 0 only.
__device__ double block_reduce(double v) {
    __shared__ double sm[16];
    __syncthreads();
    for (int off = 32; off; off >>= 1) v += __shfl_down(v, off, 64);
    const int lane = threadIdx.x & 63, wid = threadIdx.x >> 6;
    if (lane == 0) sm[wid] = v;
    __syncthreads();
    if (wid == 0) {
        const int nw = blockDim.x >> 6;
        v = (lane < nw) ? sm[lane] : 0.0;
        for (int off = 8; off; off >>= 1) v += __shfl_down(v, off, 64);
    }
    return v;
}

// Exclusive prefix over 256 threads. Caller must __syncthreads() before reusing smw.
__device__ unsigned int block_excl_scan_u32(unsigned int x, unsigned int* smw) {
    const int lane = threadIdx.x & 63, wid = threadIdx.x >> 6;
    unsigned int v = x;
    for (int d = 1; d < 64; d <<= 1) {
        unsigned int t = __shfl_up(v, d, 64);
        if (lane >= d) v += t;
    }
    if (lane == 63) smw[wid] = v;
    __syncthreads();
    unsigned int base = 0;
    for (int w = 0; w < wid; ++w) base += smw[w];
    return base + v - x;
}

// P[i] = {u, signz, beta, j1}
__global__ void prep(const float* __restrict__ x, const float* __restrict__ u,
                     const float* __restrict__ j1v,
                     const float* __restrict__ bm_p, const float* __restrict__ bp_p,
                     float4* __restrict__ P) {
    const float bm = bm_p[0], bp = bp_p[0];
    const int stride = gridDim.x * blockDim.x;
    for (int i = blockIdx.x * blockDim.x + threadIdx.x; i < N_NODES; i += stride) {
        const float z = x[4 * i + 3];
        P[i] = make_float4(u[i], (float)(z > 0.f) - (float)(z < 0.f),
                           (z < 0.f) ? bm : bp, j1v[i]);
    }
}

// per-chunk bucket histogram. hist layout: [bucket][chunk]
__global__ void k_hist(const int4* __restrict__ row4, unsigned int* __restrict__ hist) {
    __shared__ unsigned int h[NB];
    for (int i = threadIdx.x; i < NB; i += blockDim.x) h[i] = 0;
    __syncthreads();
    const int ch = blockIdx.x;
    for (int q = threadIdx.x; q < NQ; q += blockDim.x) {
        const int4 r = row4[ch * NQ + q];
        atomicAdd(&h[r.x >> WIN_SHIFT], 1u);
        atomicAdd(&h[r.y >> WIN_SHIFT], 1u);
        atomicAdd(&h[r.z >> WIN_SHIFT], 1u);
        atomicAdd(&h[r.w >> WIN_SHIFT], 1u);
    }
    __syncthreads();
    for (int i = threadIdx.x; i < NB; i += blockDim.x)
        hist[(size_t)i * NCHUNK + ch] = h[i];
}

// per-bucket exclusive scan across chunks. scanned layout: [chunk][bucket]
__global__ void k_scan1(const unsigned int* __restrict__ hist,
                        unsigned int* __restrict__ scanned,
                        unsigned int* __restrict__ total) {
    __shared__ unsigned int v[NCHUNK];
    __shared__ unsigned int smw[4];
    const int b = blockIdx.x;
    for (int i = threadIdx.x; i < NCHUNK; i += blockDim.x)
        v[i] = hist[(size_t)b * NCHUNK + i];
    __syncthreads();
    const int i0 = threadIdx.x * SC_ITEMS;
    unsigned int s = 0;
    for (int k = 0; k < SC_ITEMS; ++k) { const int i = i0 + k; if (i < NCHUNK) s += v[i]; }
    const unsigned int ex = block_excl_scan_u32(s, smw);
    if (threadIdx.x == blockDim.x - 1) total[b] = ex + s;
    unsigned int run = ex;
    for (int k = 0; k < SC_ITEMS; ++k) {
        const int i = i0 + k;
        if (i < NCHUNK) { scanned[(size_t)i * NB + b] = run; run += v[i]; }
    }
}

// bucket base offsets
__global__ void k_scan2(const unsigned int* __restrict__ total, unsigned int* __restrict__ baseb) {
    __shared__ unsigned int smw[4];
    const unsigned int x = (threadIdx.x < NB) ? total[threadIdx.x] : 0;
    const unsigned int ex = block_excl_scan_u32(x, smw);
    if (threadIdx.x < NB) baseb[threadIdx.x] = ex;
}

// LDS-staged bucket-sorted scatter + j1 loss.
__global__ void __launch_bounds__(256, 2)
k_scatter(const int4* __restrict__ row4, const int4* __restrict__ col4,
          const int4* __restrict__ attr4,
          const float4* __restrict__ cdx4, const float4* __restrict__ cdy4,
          const float4* __restrict__ clap4,
          const float4* __restrict__ P,
          const unsigned int* __restrict__ baseb,
          const unsigned int* __restrict__ scanned,
          float4* __restrict__ rec, Accum* __restrict__ acc) {
    __shared__ int   lhist[NB];
    __shared__ int   lcur[NB];
    __shared__ unsigned int lbase[NB];
    __shared__ unsigned int gdest[NB];
    __shared__ unsigned int smw[4];
    __shared__ int   s_r[CHUNK];
    __shared__ float s_ud[CHUNK];
    __shared__ int   o_r[CHUNK];
    __shared__ float o_v1[CHUNK], o_v2[CHUNK], o_v3[CHUNK];

    const int ch = blockIdx.x;
    for (int i = threadIdx.x; i < NB; i += blockDim.x) { lhist[i] = 0; lcur[i] = 0; }
    __syncthreads();

    // Pass A: read edges, gather P, local hist, j1 terms
    double j1s = 0.0;
    int hc = 0;
    for (int q = threadIdx.x; q < NQ; q += blockDim.x) {
        const int4 r4 = row4[ch * NQ + q];
        const int4 c4 = col4[ch * NQ + q];
        const int4 a4 = attr4[ch * NQ + q];
        const int* rr = (const int*)&r4;
        const int* cc = (const int*)&c4;
        const int* aa = (const int*)&a4;
#pragma unroll
        for (int k = 0; k < 4; ++k) {
            const int r = rr[k], c = cc[k];
            const float4 Pr = P[r];
            const float4 Pc = P[c];
            const float ud = Pc.x - Pr.x;
            const int i = 4 * q + k;
            s_r[i] = r;
            s_ud[i] = ud;
            atomicAdd(&lhist[r >> WIN_SHIFT], 1);
            if (aa[k] == 1) {
                const float d = Pc.y * ud - Pr.w;   // signz_dst*ud - j1_src
                j1s += (double)(d * d);
                hc++;
            }
        }
    }
    __syncthreads();

    // local exclusive scan of lhist + load global run bases
    for (int i = threadIdx.x; i < NB; i += blockDim.x)
        gdest[i] = baseb[i] + scanned[(size_t)ch * NB + i];
    const unsigned int xv = (threadIdx.x < NB) ? (unsigned int)lhist[threadIdx.x] : 0;
    const unsigned int exv = block_excl_scan_u32(xv, smw);
    if (threadIdx.x < NB) lbase[threadIdx.x] = exv;
    __syncthreads();

    // Pass B: place records into LDS in bucket-sorted local order
    for (int q = threadIdx.x; q < NQ; q += blockDim.x) {
        const float4 cx = cdx4[ch * NQ + q];
        const float4 cy = cdy4[ch * NQ + q];
        const float4 cl = clap4[ch * NQ + q];
        const float* fx = (const float*)&cx;
        const float* fy = (const float*)&cy;
        const float* fl = (const float*)&cl;
#pragma unroll
        for (int k = 0; k < 4; ++k) {
            const int i = 4 * q + k;
            const int r = s_r[i];
            const float ud = s_ud[i];
            const int b = r >> WIN_SHIFT;
            const int p = (int)lbase[b] + atomicAdd(&lcur[b], 1);
            o_r[p] = r;
            o_v1[p] = ud * fx[k];
            o_v2[p] = ud * fy[k];
            o_v3[p] = ud * fl[k];
        }
    }
    __syncthreads();

    // Pass C: stream runs to global, coalesced
    for (int i = threadIdx.x; i < CHUNK; i += blockDim.x) {
        const int r = o_r[i];
        const int b = r >> WIN_SHIFT;
        const unsigned int dest = gdest[b] + (unsigned int)(i - (int)lbase[b]);
        rec[dest] = make_float4(__int_as_float(r), o_v1[i], o_v2[i], o_v3[i]);
    }

    double t = block_reduce(j1s);
    if (threadIdx.x == 0) atomicAdd(&acc->j1_sum, t);
    t = block_reduce((double)hc);
    if (threadIdx.x == 0) atomicAdd(&acc->het_cnt, t);
}

// per-bucket LDS accumulate; emit R = {0.5*px/a^2, 0.5*py/b^2, beta*dx, beta*dy}; pde/bc.
__global__ void k_acc(const float4* __restrict__ rec,
                      const unsigned int* __restrict__ baseb,
                      const unsigned int* __restrict__ total,
                      const float4* __restrict__ P,
                      const float2* __restrict__ pos2,
                      const float* __restrict__ y, const float* __restrict__ source,
                      const float* __restrict__ a_p, const float* __restrict__ b_p,
                      float4* __restrict__ R, Accum* __restrict__ acc) {
    __shared__ float a3[WINDOW * 3];
    for (int i = threadIdx.x; i < WINDOW * 3; i += blockDim.x) a3[i] = 0.f;
    __syncthreads();
    const int b = blockIdx.x;
    const int s = (int)baseb[b];
    const int e = s + (int)total[b];
    for (int i = s + threadIdx.x; i < e; i += blockDim.x) {
        const float4 rc = rec[i];
        const int lr = (__float_as_int(rc.x) & (WINDOW - 1)) * 3;
        atomicAdd(&a3[lr + 0], rc.y);
        atomicAdd(&a3[lr + 1], rc.z);
        atomicAdd(&a3[lr + 2], rc.w);
    }
    __syncthreads();
    const float av = a_p[0], bv = b_p[0];
    const float ha = 0.5f / (av * av), hb = 0.5f / (bv * bv);
    double pde = 0.0, bcs = 0.0;
    int bcc = 0;
    const int n0 = b << WIN_SHIFT;
    const int n1 = min(n0 + WINDOW, N_NODES);
    for (int i = n0 + threadIdx.x; i < n1; i += blockDim.x) {
        const int l = (i - n0) * 3;
        const float4 Pi = P[i];
        const float beta = Pi.z;
        const float2 p = pos2[i];
        R[i] = make_float4(p.x * ha, p.y * hb, beta * a3[l], beta * a3[l + 1]);
        const float res = -a3[l + 2] - source[i] / beta;
        pde += (double)(res * res);
        if (fabsf(p.x) > 0.99f || fabsf(p.y) > 0.99f) {
            const float d = Pi.x - y[i];
            bcs += (double)(d * d);
            bcc++;
        }
    }
    double t = block_reduce(pde);
    if (threadIdx.x == 0) atomicAdd(&acc->pde_sum, t);
    t = block_reduce(bcs);
    if (threadIdx.x == 0) atomicAdd(&acc->bc_sum, t);
    t = block_reduce((double)bcc);
    if (threadIdx.x == 0) atomicAdd(&acc->bc_cnt, t);
}

// j2 over raw edges: 2x16B R gathers + 4B signz gather per het edge.
__global__ void k_pass2(const int4* __restrict__ row4, const int4* __restrict__ col4,
                        const int4* __restrict__ attr4,
                        const float4* __restrict__ R, const float* __restrict__ Pf,
                        const float* __restrict__ c_p,
                        const float* __restrict__ bm_p, const float* __restrict__ bp_p,
                        Accum* __restrict__ acc) {
    const float tgt = 2.f * (c_p[0] * bp_p[0] - bm_p[0]);
    double j2s = 0.0;
    const int stride = gridDim.x * blockDim.x;
    const int NQT = N_EDGES / 4;
    for (int q = blockIdx.x * blockDim.x + threadIdx.x; q < NQT; q += stride) {
        const int4 r4 = row4[q];
        const int4 c4 = col4[q];
        const int4 a4 = attr4[q];
        const int* rr = (const int*)&r4;
        const int* cc = (const int*)&c4;
        const int* aa = (const int*)&a4;
#pragma unroll
        for (int k = 0; k < 4; ++k) {
            if (aa[k] != 1) continue;
            const int r = rr[k], c = cc[k];
            const float4 Rr = R[r];
            const float4 Rc = R[c];
            const float nx = Rr.x + Rc.x;
            const float ny = Rr.y + Rc.y;
            const float nrm = fmaxf(sqrtf(nx * nx + ny * ny), EPSF);
            const float B = ((Rc.z - Rr.z) * nx + (Rc.w - Rr.w) * ny) / nrm;
            const float s = Pf[4 * c + 1];          // signz_dst
            const float d = s * B - tgt * nrm;
            j2s += (double)(d * d);
        }
    }
    const double t = block_reduce(j2s);
    if (threadIdx.x == 0) atomicAdd(&acc->j2_sum, t);
}

// ---------------- fallback (small ws): device atomics ----------------
__global__ void fb_edge1(const float4* __restrict__ P,
                         const float* __restrict__ cdx, const float* __restrict__ cdy,
                         const float* __restrict__ clap,
                         const int* __restrict__ row, const int* __restrict__ col,
                         const int* __restrict__ attr,
                         float* __restrict__ rep, Accum* __restrict__ acc) {
    double j1s = 0.0;
    int hc = 0;
    const int stride = gridDim.x * blockDim.x;
    for (int e = blockIdx.x * blockDim.x + threadIdx.x; e < N_EDGES; e += stride) {
        const int r = row[e], c = col[e];
        const float4 Pr = P[r], Pc = P[c];
        const float ud = Pc.x - Pr.x;
        atomicAdd(&rep[4 * (size_t)r + 0], ud * cdx[e]);
        atomicAdd(&rep[4 * (size_t)r + 1], ud * cdy[e]);
        atomicAdd(&rep[4 * (size_t)r + 2], ud * clap[e]);
        if (attr[e] == 1) {
            const float d = Pc.y * ud - Pr.w;
            j1s += (double)(d * d);
            hc++;
        }
    }
    double t = block_reduce(j1s);
    if (threadIdx.x == 0) atomicAdd(&acc->j1_sum, t);
    t = block_reduce((double)hc);
    if (threadIdx.x == 0) atomicAdd(&acc->het_cnt, t);
}

__global__ void fb_reduce(const float4* __restrict__ rep,
                          const float4* __restrict__ P,
                          const float2* __restrict__ pos2,
                          const float* __restrict__ y, const float* __restrict__ source,
                          const float* __restrict__ a_p, const float* __restrict__ b_p,
                          float4* __restrict__ R, Accum* __restrict__ acc) {
    const float av = a_p[0], bv = b_p[0];
    const float ha = 0.5f / (av * av), hb = 0.5f / (bv * bv);
    double pde = 0.0, bcs = 0.0;
    int bcc = 0;
    const int stride = gridDim.x * blockDim.x;
    for (int i = blockIdx.x * blockDim.x + threadIdx.x; i < N_NODES; i += stride) {
        const float4 v = rep[i];
        const float4 Pi = P[i];
        const float2 p = pos2[i];
        R[i] = make_float4(p.x * ha, p.y * hb, Pi.z * v.x, Pi.z * v.y);
        const float res = -v.z - source[i] / Pi.z;
        pde += (double)(res * res);
        if (fabsf(p.x) > 0.99f || fabsf(p.y) > 0.99f) {
            const float d = Pi.x - y[i];
            bcs += (double)(d * d);
            bcc++;
        }
    }
    double t = block_reduce(pde);
    if (threadIdx.x == 0) atomicAdd(&acc->pde_sum, t);
    t = block_reduce(bcs);
    if (threadIdx.x == 0) atomicAdd(&acc->bc_sum, t);
    t = block_reduce((double)bcc);
    if (threadIdx.x == 0) atomicAdd(&acc->bc_cnt, t);
}

__global__ void finalize(const Accum* __restrict__ acc, float* __restrict__ out) {
    if (threadIdx.x == 0 && blockIdx.x == 0) {
        const double loss_pde = acc->pde_sum / (double)N_NODES;
        const double loss_bc  = acc->bc_sum / fmax(acc->bc_cnt, 1.0);
        const double hc       = fmax(acc->het_cnt, 1.0);
        out[0] = (float)(loss_pde + 100.0 * loss_bc +
                         10.0 * (acc->j1_sum / hc) + 10.0 * (acc->j2_sum / hc));
    }
}

extern "C" void kernel_launch(void* const* d_in, const int* in_sizes, int n_in,
                              void* d_out, int out_size, void* d_ws, size_t ws_size,
                              hipStream_t stream) {
    const float* u_pred = (const float*)d_in[0];
    const float* x      = (const float*)d_in[1];
    const float2* pos2  = (const float2*)d_in[2];
    const float* y      = (const float*)d_in[3];
    const float* source = (const float*)d_in[4];
    const float* j1v    = (const float*)d_in[5];
    const float* cdx    = (const float*)d_in[6];
    const float* cdy    = (const float*)d_in[7];
    const float* clap   = (const float*)d_in[8];
    const float* a_p    = (const float*)d_in[9];
    const float* b_p    = (const float*)d_in[10];
    const float* c_p    = (const float*)d_in[11];
    const float* bm_p   = (const float*)d_in[12];
    const float* bp_p   = (const float*)d_in[13];
    const int* row_idx  = (const int*)d_in[14];
    const int* col_idx  = row_idx + N_EDGES;
    const int* eattr    = (const int*)d_in[15];

    char* base_p = (char*)d_ws;
    size_t off = 0;
    auto alloc = [&](size_t bytes) { void* p = base_p + off; off = (off + bytes + 63) & ~(size_t)63; return p; };

    Accum* acc = (Accum*)alloc(sizeof(Accum));
    float4* P  = (float4*)alloc((size_t)N_NODES * 16);
    float4* R  = (float4*)alloc((size_t)N_NODES * 16);
    unsigned int* hist    = (unsigned int*)alloc((size_t)NB * NCHUNK * 4);
    unsigned int* scanned = (unsigned int*)alloc((size_t)NCHUNK * NB * 4);
    unsigned int* total   = (unsigned int*)alloc(NB * 4);
    unsigned int* baseb   = (unsigned int*)alloc(NB * 4);
    const size_t need_fb = off + (size_t)N_NODES * 16;   // fallback: rep after misc
    float4* rec = (float4*)alloc((size_t)N_EDGES * 16);
    const size_t need_full = off;

    const int threads = 256;
    const int nblocks = (N_NODES + threads - 1) / threads;

    hipMemsetAsync(d_ws, 0, 64, stream);
    prep<<<nblocks, threads, 0, stream>>>(x, u_pred, j1v, bm_p, bp_p, P);

    if (ws_size >= need_full) {
        k_hist<<<NCHUNK, threads, 0, stream>>>((const int4*)row_idx, hist);
        k_scan1<<<NB, threads, 0, stream>>>(hist, scanned, total);
        k_scan2<<<1, threads, 0, stream>>>(total, baseb);
        k_scatter<<<NCHUNK, threads, 0, stream>>>((const int4*)row_idx, (const int4*)col_idx,
                                                  (const int4*)eattr,
                                                  (const float4*)cdx, (const float4*)cdy,
                                                  (const float4*)clap,
                                                  P, baseb, scanned, rec, acc);
        k_acc<<<NB, threads, 0, stream>>>(rec, baseb, total, P, pos2, y, source,
                                          a_p, b_p, R, acc);
    } else {
        float4* rep = (float4*)(base_p + need_fb - (size_t)N_NODES * 16);
        hipMemsetAsync(rep, 0, (size_t)N_NODES * 16, stream);
        fb_edge1<<<2048, threads, 0, stream>>>(P, cdx, cdy, clap,
                                               row_idx, col_idx, eattr, (float*)rep, acc);
        fb_reduce<<<nblocks, threads, 0, stream>>>(rep, P, pos2, y, source, a_p, b_p, R, acc);
    }

    k_pass2<<<2048, threads, 0, stream>>>((const int4*)row_idx, (const int4*)col_idx,
                                          (const int4*)eattr, R, (const float*)P,
                                          c_p, bm_p, bp_p, acc);
    finalize<<<1, 64, 0, stream>>>(acc, (float*)d_out);
}

// Round 5
// 496.180 us; speedup vs baseline: 3.2706x; 1.1660x over previous
//
#include <hip/hip_runtime.h>
#include <hip/hip_fp16.h>

#define N_NODES 500000
#define N_EDGES 8000000
#define EPSF 1e-8f

#define WIN_SHIFT 11
#define WINDOW 2048
#define NB 245                       // ceil(500000/2048)
#define CHUNK 2000                   // edges per scatter chunk
#define NQ (CHUNK / 4)
#define NCHUNK 4000                  // 8e6 / 2000
#define SC_ITEMS 16                  // 256*16 >= NCHUNK

typedef int   v4i __attribute__((ext_vector_type(4)));
typedef float v4f __attribute__((ext_vector_type(4)));

struct Accum { double pde_sum, bc_sum, bc_cnt, j1_sum, j2_sum, het_cnt; };

__device__ __forceinline__ unsigned short f2h(float f) {
    __half h = __float2half(f);
    return __half_as_ushort(h);
}
__device__ __forceinline__ float h2f(unsigned short u) {
    return __half2float(__ushort_as_half(u));
}

// Block-wide f64 sum. Valid on thread 0 only.
__device__ double block_reduce(double v) {
    __shared__ double sm[16];
    __syncthreads();
    for (int off = 32; off; off >>= 1) v += __shfl_down(v, off, 64);
    const int lane = threadIdx.x & 63, wid = threadIdx.x >> 6;
    if (lane == 0) sm[wid] = v;
    __syncthreads();
    if (wid == 0) {
        const int nw = blockDim.x >> 6;
        v = (lane < nw) ? sm[lane] : 0.0;
        for (int off = 8; off; off >>= 1) v += __shfl_down(v, off, 64);
    }
    return v;
}

// Exclusive prefix over 256 threads. Caller must __syncthreads() before reusing smw.
__device__ unsigned int block_excl_scan_u32(unsigned int x, unsigned int* smw) {
    const int lane = threadIdx.x & 63, wid = threadIdx.x >> 6;
    unsigned int v = x;
    for (int d = 1; d < 64; d <<= 1) {
        unsigned int t = __shfl_up(v, d, 64);
        if (lane >= d) v += t;
    }
    if (lane == 63) smw[wid] = v;
    __syncthreads();
    unsigned int base = 0;
    for (int w = 0; w < wid; ++w) base += smw[w];
    return base + v - x;
}

// compact sz[i] = sign(z_i)
__global__ void prep(const float* __restrict__ x, float* __restrict__ sz) {
    const int stride = gridDim.x * blockDim.x;
    for (int i = blockIdx.x * blockDim.x + threadIdx.x; i < N_NODES; i += stride) {
        const float z = x[4 * i + 3];
        sz[i] = (float)(z > 0.f) - (float)(z < 0.f);
    }
}

// per-chunk bucket histogram. hist layout: [bucket][chunk]
__global__ void k_hist(const v4i* __restrict__ row4, unsigned int* __restrict__ hist) {
    __shared__ unsigned int h[NB];
    for (int i = threadIdx.x; i < NB; i += blockDim.x) h[i] = 0;
    __syncthreads();
    const int ch = blockIdx.x;
    for (int q = threadIdx.x; q < NQ; q += blockDim.x) {
        const v4i r = __builtin_nontemporal_load(&row4[ch * NQ + q]);
        atomicAdd(&h[r[0] >> WIN_SHIFT], 1u);
        atomicAdd(&h[r[1] >> WIN_SHIFT], 1u);
        atomicAdd(&h[r[2] >> WIN_SHIFT], 1u);
        atomicAdd(&h[r[3] >> WIN_SHIFT], 1u);
    }
    __syncthreads();
    for (int i = threadIdx.x; i < NB; i += blockDim.x)
        hist[(size_t)i * NCHUNK + ch] = h[i];
}

// per-bucket exclusive scan across chunks. scanned layout: [chunk][bucket]
__global__ void k_scan1(const unsigned int* __restrict__ hist,
                        unsigned int* __restrict__ scanned,
                        unsigned int* __restrict__ total) {
    __shared__ unsigned int v[NCHUNK];
    __shared__ unsigned int smw[4];
    const int b = blockIdx.x;
    for (int i = threadIdx.x; i < NCHUNK; i += blockDim.x)
        v[i] = hist[(size_t)b * NCHUNK + i];
    __syncthreads();
    const int i0 = threadIdx.x * SC_ITEMS;
    unsigned int s = 0;
    for (int k = 0; k < SC_ITEMS; ++k) { const int i = i0 + k; if (i < NCHUNK) s += v[i]; }
    const unsigned int ex = block_excl_scan_u32(s, smw);
    if (threadIdx.x == blockDim.x - 1) total[b] = ex + s;
    unsigned int run = ex;
    for (int k = 0; k < SC_ITEMS; ++k) {
        const int i = i0 + k;
        if (i < NCHUNK) { scanned[(size_t)i * NB + b] = run; run += v[i]; }
    }
}

__global__ void k_scan2(const unsigned int* __restrict__ total, unsigned int* __restrict__ baseb) {
    __shared__ unsigned int smw[4];
    const unsigned int x = (threadIdx.x < NB) ? total[threadIdx.x] : 0;
    const unsigned int ex = block_excl_scan_u32(x, smw);
    if (threadIdx.x < NB) baseb[threadIdx.x] = ex;
}

// Single-pass LDS-staged bucket-sorted scatter + j1 loss.
__global__ void __launch_bounds__(256, 4)
k_scatter(const v4i* __restrict__ row4, const v4i* __restrict__ col4,
          const v4i* __restrict__ attr4,
          const v4f* __restrict__ cdx4, const v4f* __restrict__ cdy4,
          const v4f* __restrict__ clap4,
          const float* __restrict__ u, const float* __restrict__ sz,
          const float* __restrict__ j1v,
          const unsigned int* __restrict__ baseb,
          const unsigned int* __restrict__ scanned,
          const unsigned int* __restrict__ hist,
          v4f* __restrict__ rec, Accum* __restrict__ acc) {
    __shared__ int          lcur[NB];
    __shared__ unsigned int lbase[NB];
    __shared__ unsigned int gdest[NB];
    __shared__ unsigned int smw[4];
    __shared__ v4f          o4[CHUNK];

    const int ch = blockIdx.x;
    for (int i = threadIdx.x; i < NB; i += blockDim.x) {
        lcur[i]  = 0;
        gdest[i] = baseb[i] + scanned[(size_t)ch * NB + i];
    }
    const unsigned int xv = (threadIdx.x < NB)
        ? hist[(size_t)threadIdx.x * NCHUNK + ch] : 0;
    const unsigned int exv = block_excl_scan_u32(xv, smw);
    if (threadIdx.x < NB) lbase[threadIdx.x] = exv;
    __syncthreads();

    double j1s = 0.0;
    int hc = 0;
    for (int q = threadIdx.x; q < NQ; q += blockDim.x) {
        const v4i r4 = __builtin_nontemporal_load(&row4[ch * NQ + q]);
        const v4i c4 = __builtin_nontemporal_load(&col4[ch * NQ + q]);
        const v4i a4 = __builtin_nontemporal_load(&attr4[ch * NQ + q]);
        const v4f cx = __builtin_nontemporal_load(&cdx4[ch * NQ + q]);
        const v4f cy = __builtin_nontemporal_load(&cdy4[ch * NQ + q]);
        const v4f cl = __builtin_nontemporal_load(&clap4[ch * NQ + q]);
#pragma unroll
        for (int k = 0; k < 4; ++k) {
            const int r = r4[k], c = c4[k];
            const float ud = u[c] - u[r];
            const int b = r >> WIN_SHIFT;
            const int p = (int)lbase[b] + atomicAdd(&lcur[b], 1);
            v4f rc;
            rc[0] = __int_as_float(r);
            rc[1] = ud * cx[k];
            rc[2] = ud * cy[k];
            rc[3] = ud * cl[k];
            o4[p] = rc;
            if (a4[k] == 1) {
                const float d = sz[c] * ud - j1v[r];
                j1s += (double)(d * d);
                hc++;
            }
        }
    }
    __syncthreads();

    // stream runs to global, coalesced, non-temporal
    for (int i = threadIdx.x; i < CHUNK; i += blockDim.x) {
        const v4f rc = o4[i];
        const int b = __float_as_int(rc[0]) >> WIN_SHIFT;
        const unsigned int dest = gdest[b] + (unsigned int)(i - (int)lbase[b]);
        __builtin_nontemporal_store(rc, &rec[dest]);
    }

    double t = block_reduce(j1s);
    if (threadIdx.x == 0) atomicAdd(&acc->j1_sum, t);
    t = block_reduce((double)hc);
    if (threadIdx.x == 0) atomicAdd(&acc->het_cnt, t);
}

// per-bucket LDS accumulate; emit Q = f16x4{hx, hy, beta*dx, beta*dy}; pde/bc.
__global__ void k_acc(const v4f* __restrict__ rec,
                      const unsigned int* __restrict__ baseb,
                      const unsigned int* __restrict__ total,
                      const float* __restrict__ u, const float* __restrict__ sz,
                      const float2* __restrict__ pos2,
                      const float* __restrict__ y, const float* __restrict__ source,
                      const float* __restrict__ a_p, const float* __restrict__ b_p,
                      const float* __restrict__ bm_p, const float* __restrict__ bp_p,
                      ushort4* __restrict__ Q, Accum* __restrict__ acc) {
    __shared__ float a3[WINDOW * 3];
    for (int i = threadIdx.x; i < WINDOW * 3; i += blockDim.x) a3[i] = 0.f;
    __syncthreads();
    const int b = blockIdx.x;
    const int s = (int)baseb[b];
    const int e = s + (int)total[b];
    for (int i = s + threadIdx.x; i < e; i += blockDim.x) {
        const v4f rc = __builtin_nontemporal_load(&rec[i]);
        const int lr = (__float_as_int(rc[0]) & (WINDOW - 1)) * 3;
        atomicAdd(&a3[lr + 0], rc[1]);
        atomicAdd(&a3[lr + 1], rc[2]);
        atomicAdd(&a3[lr + 2], rc[3]);
    }
    __syncthreads();
    const float av = a_p[0], bv = b_p[0], bm = bm_p[0], bp = bp_p[0];
    const float ha = 0.5f / (av * av), hb = 0.5f / (bv * bv);
    double pde = 0.0, bcs = 0.0;
    int bcc = 0;
    const int n0 = b << WIN_SHIFT;
    const int n1 = min(n0 + WINDOW, N_NODES);
    for (int i = n0 + threadIdx.x; i < n1; i += blockDim.x) {
        const int l = (i - n0) * 3;
        const float beta = (sz[i] < 0.f) ? bm : bp;
        const float2 p = pos2[i];
        ushort4 qo;
        qo.x = f2h(p.x * ha);
        qo.y = f2h(p.y * hb);
        qo.z = f2h(beta * a3[l]);
        qo.w = f2h(beta * a3[l + 1]);
        Q[i] = qo;
        const float res = -a3[l + 2] - source[i] / beta;
        pde += (double)(res * res);
        if (fabsf(p.x) > 0.99f || fabsf(p.y) > 0.99f) {
            const float d = u[i] - y[i];
            bcs += (double)(d * d);
            bcc++;
        }
    }
    double t = block_reduce(pde);
    if (threadIdx.x == 0) atomicAdd(&acc->pde_sum, t);
    t = block_reduce(bcs);
    if (threadIdx.x == 0) atomicAdd(&acc->bc_sum, t);
    t = block_reduce((double)bcc);
    if (threadIdx.x == 0) atomicAdd(&acc->bc_cnt, t);
}

// j2 over raw edges: 2x8B Q gathers + 4B sz gather per het edge.
__global__ void k_pass2(const v4i* __restrict__ row4, const v4i* __restrict__ col4,
                        const v4i* __restrict__ attr4,
                        const ushort4* __restrict__ Q, const float* __restrict__ sz,
                        const float* __restrict__ c_p,
                        const float* __restrict__ bm_p, const float* __restrict__ bp_p,
                        Accum* __restrict__ acc) {
    const float tgt = 2.f * (c_p[0] * bp_p[0] - bm_p[0]);
    double j2s = 0.0;
    const int stride = gridDim.x * blockDim.x;
    const int NQT = N_EDGES / 4;
    for (int q = blockIdx.x * blockDim.x + threadIdx.x; q < NQT; q += stride) {
        const v4i r4 = __builtin_nontemporal_load(&row4[q]);
        const v4i c4 = __builtin_nontemporal_load(&col4[q]);
        const v4i a4 = __builtin_nontemporal_load(&attr4[q]);
#pragma unroll
        for (int k = 0; k < 4; ++k) {
            if (a4[k] != 1) continue;
            const int r = r4[k], c = c4[k];
            const ushort4 qr = Q[r];
            const ushort4 qc = Q[c];
            const float nx = h2f(qr.x) + h2f(qc.x);
            const float ny = h2f(qr.y) + h2f(qc.y);
            const float nrm = fmaxf(sqrtf(nx * nx + ny * ny), EPSF);
            const float B = ((h2f(qc.z) - h2f(qr.z)) * nx +
                             (h2f(qc.w) - h2f(qr.w)) * ny) / nrm;
            const float d = sz[c] * B - tgt * nrm;
            j2s += (double)(d * d);
        }
    }
    const double t = block_reduce(j2s);
    if (threadIdx.x == 0) atomicAdd(&acc->j2_sum, t);
}

// ---------------- fallback (small ws): device atomics ----------------
__global__ void fb_edge1(const float* __restrict__ u, const float* __restrict__ sz,
                         const float* __restrict__ j1v,
                         const float* __restrict__ cdx, const float* __restrict__ cdy,
                         const float* __restrict__ clap,
                         const int* __restrict__ row, const int* __restrict__ col,
                         const int* __restrict__ attr,
                         float* __restrict__ rep, Accum* __restrict__ acc) {
    double j1s = 0.0;
    int hc = 0;
    const int stride = gridDim.x * blockDim.x;
    for (int e = blockIdx.x * blockDim.x + threadIdx.x; e < N_EDGES; e += stride) {
        const int r = row[e], c = col[e];
        const float ud = u[c] - u[r];
        atomicAdd(&rep[4 * (size_t)r + 0], ud * cdx[e]);
        atomicAdd(&rep[4 * (size_t)r + 1], ud * cdy[e]);
        atomicAdd(&rep[4 * (size_t)r + 2], ud * clap[e]);
        if (attr[e] == 1) {
            const float d = sz[c] * ud - j1v[r];
            j1s += (double)(d * d);
            hc++;
        }
    }
    double t = block_reduce(j1s);
    if (threadIdx.x == 0) atomicAdd(&acc->j1_sum, t);
    t = block_reduce((double)hc);
    if (threadIdx.x == 0) atomicAdd(&acc->het_cnt, t);
}

__global__ void fb_reduce(const float4* __restrict__ rep,
                          const float* __restrict__ u, const float* __restrict__ sz,
                          const float2* __restrict__ pos2,
                          const float* __restrict__ y, const float* __restrict__ source,
                          const float* __restrict__ a_p, const float* __restrict__ b_p,
                          const float* __restrict__ bm_p, const float* __restrict__ bp_p,
                          ushort4* __restrict__ Q, Accum* __restrict__ acc) {
    const float av = a_p[0], bv = b_p[0], bm = bm_p[0], bp = bp_p[0];
    const float ha = 0.5f / (av * av), hb = 0.5f / (bv * bv);
    double pde = 0.0, bcs = 0.0;
    int bcc = 0;
    const int stride = gridDim.x * blockDim.x;
    for (int i = blockIdx.x * blockDim.x + threadIdx.x; i < N_NODES; i += stride) {
        const float4 v = rep[i];
        const float beta = (sz[i] < 0.f) ? bm : bp;
        const float2 p = pos2[i];
        ushort4 qo;
        qo.x = f2h(p.x * ha);
        qo.y = f2h(p.y * hb);
        qo.z = f2h(beta * v.x);
        qo.w = f2h(beta * v.y);
        Q[i] = qo;
        const float res = -v.z - source[i] / beta;
        pde += (double)(res * res);
        if (fabsf(p.x) > 0.99f || fabsf(p.y) > 0.99f) {
            const float d = u[i] - y[i];
            bcs += (double)(d * d);
            bcc++;
        }
    }
    double t = block_reduce(pde);
    if (threadIdx.x == 0) atomicAdd(&acc->pde_sum, t);
    t = block_reduce(bcs);
    if (threadIdx.x == 0) atomicAdd(&acc->bc_sum, t);
    t = block_reduce((double)bcc);
    if (threadIdx.x == 0) atomicAdd(&acc->bc_cnt, t);
}

__global__ void finalize(const Accum* __restrict__ acc, float* __restrict__ out) {
    if (threadIdx.x == 0 && blockIdx.x == 0) {
        const double loss_pde = acc->pde_sum / (double)N_NODES;
        const double loss_bc  = acc->bc_sum / fmax(acc->bc_cnt, 1.0);
        const double hc       = fmax(acc->het_cnt, 1.0);
        out[0] = (float)(loss_pde + 100.0 * loss_bc +
                         10.0 * (acc->j1_sum / hc) + 10.0 * (acc->j2_sum / hc));
    }
}

extern "C" void kernel_launch(void* const* d_in, const int* in_sizes, int n_in,
                              void* d_out, int out_size, void* d_ws, size_t ws_size,
                              hipStream_t stream) {
    const float* u_pred = (const float*)d_in[0];
    const float* x      = (const float*)d_in[1];
    const float2* pos2  = (const float2*)d_in[2];
    const float* y      = (const float*)d_in[3];
    const float* source = (const float*)d_in[4];
    const float* j1v    = (const float*)d_in[5];
    const float* cdx    = (const float*)d_in[6];
    const float* cdy    = (const float*)d_in[7];
    const float* clap   = (const float*)d_in[8];
    const float* a_p    = (const float*)d_in[9];
    const float* b_p    = (const float*)d_in[10];
    const float* c_p    = (const float*)d_in[11];
    const float* bm_p   = (const float*)d_in[12];
    const float* bp_p   = (const float*)d_in[13];
    const int* row_idx  = (const int*)d_in[14];
    const int* col_idx  = row_idx + N_EDGES;
    const int* eattr    = (const int*)d_in[15];

    char* base_p = (char*)d_ws;
    size_t off = 0;
    auto alloc = [&](size_t bytes) { void* p = base_p + off; off = (off + bytes + 63) & ~(size_t)63; return p; };

    Accum* acc = (Accum*)alloc(sizeof(Accum));
    float* sz  = (float*)alloc((size_t)N_NODES * 4);
    ushort4* Q = (ushort4*)alloc((size_t)N_NODES * 8);
    unsigned int* hist    = (unsigned int*)alloc((size_t)NB * NCHUNK * 4);
    unsigned int* scanned = (unsigned int*)alloc((size_t)NCHUNK * NB * 4);
    unsigned int* total   = (unsigned int*)alloc(NB * 4);
    unsigned int* baseb   = (unsigned int*)alloc(NB * 4);
    const size_t need_fb = off + (size_t)N_NODES * 16;
    v4f* rec = (v4f*)alloc((size_t)N_EDGES * 16);
    const size_t need_full = off;

    const int threads = 256;
    const int nblocks = (N_NODES + threads - 1) / threads;

    hipMemsetAsync(d_ws, 0, 64, stream);
    prep<<<nblocks, threads, 0, stream>>>(x, sz);

    if (ws_size >= need_full) {
        k_hist<<<NCHUNK, threads, 0, stream>>>((const v4i*)row_idx, hist);
        k_scan1<<<NB, threads, 0, stream>>>(hist, scanned, total);
        k_scan2<<<1, threads, 0, stream>>>(total, baseb);
        k_scatter<<<NCHUNK, threads, 0, stream>>>((const v4i*)row_idx, (const v4i*)col_idx,
                                                  (const v4i*)eattr,
                                                  (const v4f*)cdx, (const v4f*)cdy,
                                                  (const v4f*)clap,
                                                  u_pred, sz, j1v,
                                                  baseb, scanned, hist, rec, acc);
        k_acc<<<NB, threads, 0, stream>>>(rec, baseb, total, u_pred, sz, pos2, y, source,
                                          a_p, b_p, bm_p, bp_p, Q, acc);
    } else {
        float4* rep = (float4*)(base_p + need_fb - (size_t)N_NODES * 16);
        hipMemsetAsync(rep, 0, (size_t)N_NODES * 16, stream);
        fb_edge1<<<2048, threads, 0, stream>>>(u_pred, sz, j1v, cdx, cdy, clap,
                                               row_idx, col_idx, eattr, (float*)rep, acc);
        fb_reduce<<<nblocks, threads, 0, stream>>>(rep, u_pred, sz, pos2, y, source,
                                                   a_p, b_p, bm_p, bp_p, Q, acc);
    }

    k_pass2<<<2048, threads, 0, stream>>>((const v4i*)row_idx, (const v4i*)col_idx,
                                          (const v4i*)eattr, Q, sz,
                                          c_p, bm_p, bp_p, acc);
    finalize<<<1, 64, 0, stream>>>(acc, (float*)d_out);
}